// Round 1
// baseline (696.728 us; speedup 1.0000x reference)
//
#include <hip/hip_runtime.h>
#include <math.h>

#ifndef __has_builtin
#define __has_builtin(x) 0
#endif
#if __has_builtin(__builtin_amdgcn_exp2f)
#define EXP2F(x) __builtin_amdgcn_exp2f(x)
#else
#define EXP2F(x) exp2f(x)
#endif

#define L2E 1.44269504088896340736f

#define NBATCH 2
#define NC 21
#define NCP 24      // channels padded to float4 multiple; pads held at 0
#define HH 64
#define WW 64
#define NP 4096
#define KR 35
#define KS 71

// ws layout (float offsets); all 16B-aligned
#define OFF_FEATP 0         // [NB][P][8]  {f0..f4, h, 0, 0}   raw feats
#define OFF_FEATQ 65536     // [NB][P][8]  {L*f0..L*f4, h, 0,0} pre-scaled feats
#define OFF_UT    131072    // [NB][P][24] log-unary, transposed
#define OFF_QT    327680    // [NB][P][24] current q, transposed (pads 0)
#define OFF_TMP   524288    // [NB][NC][H][W] conv-y output
#define OFF_QSF   696320    // [NB][NC][H][W] conv-x output
#define OFF_G1    868352    // [71] 1-D gaussian (pad to 128)
#define OFF_PART  868480    // [S][NB][P][24] bilateral partials

#define PTILES 8            // p-tiles per batch: 512 p per block, 2 per thread

static __device__ __forceinline__ void fma4(float4& a, float k, const float4& v) {
    a.x = fmaf(k, v.x, a.x);
    a.y = fmaf(k, v.y, a.y);
    a.z = fmaf(k, v.z, a.z);
    a.w = fmaf(k, v.w, a.w);
}

__global__ __launch_bounds__(256) void setup_kernel(
    const float* __restrict__ unary, const float* __restrict__ ref,
    const float* __restrict__ kstd, float* __restrict__ ws,
    float* __restrict__ outq)
{
    int gid = blockIdx.x * 256 + threadIdx.x;
    if (gid < KS) {
        // normalized 1-D gaussian: separable factor of gk (outer(g1,g1) == gk)
        float s = 0.f;
        for (int j = 0; j < KS; ++j) {
            float d = (float)(j - KR);
            s += expf(-d * d * (1.0f / 72.0f));
        }
        float d = (float)(gid - KR);
        ws[OFF_G1 + gid] = expf(-d * d * (1.0f / 72.0f)) / s;
    }
    if (gid >= NBATCH * NP) return;
    int n = gid >> 12, p = gid & (NP - 1);
    int y = p >> 6, x = p & 63;
    float k0 = kstd[0], k1 = kstd[1], k2 = kstd[2], k3 = kstd[3], k4 = kstd[4];
    const float* rp = ref + n * 3 * NP + p;
    float f0 = (float)y / k0;
    float f1 = (float)x / k1;
    float f2 = rp[0]      / k2;
    float f3 = rp[NP]     / k3;
    float f4 = rp[2 * NP] / k4;
    float sq = f0*f0 + f1*f1 + f2*f2 + f3*f3 + f4*f4;
    float h  = -0.5f * L2E * sq;   // exponent(p,q) = L*dot(fp,fq) + h_p + h_q
    float* fp = ws + OFF_FEATP + gid * 8;
    fp[0]=f0; fp[1]=f1; fp[2]=f2; fp[3]=f3; fp[4]=f4; fp[5]=h; fp[6]=0.f; fp[7]=0.f;
    float* fq = ws + OFF_FEATQ + gid * 8;
    fq[0]=L2E*f0; fq[1]=L2E*f1; fq[2]=L2E*f2; fq[3]=L2E*f3; fq[4]=L2E*f4;
    fq[5]=h; fq[6]=0.f; fq[7]=0.f;

    // U = log(clip(unary)), q0 = softmax(U)
    float U[NC], e[NC];
    const float* up = unary + n * NC * NP + p;
    float m = -1e30f;
    for (int c = 0; c < NC; ++c) {
        float u = up[c * NP];
        u = fminf(fmaxf(u, 1e-5f), 1.0f);
        U[c] = logf(u);
        m = fmaxf(m, U[c]);
    }
    float ssum = 0.f;
    for (int c = 0; c < NC; ++c) { e[c] = EXP2F(L2E * (U[c] - m)); ssum += e[c]; }
    float inv = 1.0f / ssum;
    float* ut = ws + OFF_UT + gid * NCP;
    float* qt = ws + OFF_QT + gid * NCP;
    for (int c = 0; c < NC; ++c) {
        float qv = e[c] * inv;
        ut[c] = U[c];
        qt[c] = qv;
        outq[(n * NC + c) * NP + p] = qv;   // planar q0 (d_out doubles as buffer)
    }
    for (int c = NC; c < NCP; ++c) { ut[c] = 0.f; qt[c] = 0.f; }
}

// blocks [0, nbBil): bilateral partial sums.  blocks [nbBil, ...): conv-y.
__global__ __launch_bounds__(256) void bilat_convy_kernel(
    float* __restrict__ ws, const float* __restrict__ qplanar,
    int nbBil, int S)
{
    int b = blockIdx.x;
    int tid = threadIdx.x;
    if (b < nbBil) {
        int n  = b & 1;
        int pt = (b >> 1) & (PTILES - 1);
        int s  = b >> 4;
        int chunk = NP / S;
        int p0 = pt * 512 + tid;
        int p1 = p0 + 256;
        const float* fpA = ws + OFF_FEATP + (n * NP + p0) * 8;
        const float* fpB = ws + OFF_FEATP + (n * NP + p1) * 8;
        float a0=fpA[0], a1=fpA[1], a2=fpA[2], a3=fpA[3], a4=fpA[4], ah=fpA[5];
        float b0=fpB[0], b1=fpB[1], b2=fpB[2], b3=fpB[3], b4=fpB[4], bh=fpB[5];
        float4 accA[6], accB[6];
        #pragma unroll
        for (int k = 0; k < 6; ++k) {
            accA[k] = make_float4(0.f, 0.f, 0.f, 0.f);
            accB[k] = make_float4(0.f, 0.f, 0.f, 0.f);
        }
        int qbase = n * NP + s * chunk;
        const float4* fq4 = (const float4*)(ws + OFF_FEATQ) + qbase * 2;
        const float4* qv4 = (const float4*)(ws + OFF_QT)    + qbase * 6;
        #pragma unroll 2
        for (int j = 0; j < chunk; ++j) {
            float4 fa = fq4[2 * j], fb = fq4[2 * j + 1];
            float eA = ah + fb.y;
            eA = fmaf(a0, fa.x, eA); eA = fmaf(a1, fa.y, eA);
            eA = fmaf(a2, fa.z, eA); eA = fmaf(a3, fa.w, eA);
            eA = fmaf(a4, fb.x, eA);
            float eB = bh + fb.y;
            eB = fmaf(b0, fa.x, eB); eB = fmaf(b1, fa.y, eB);
            eB = fmaf(b2, fa.z, eB); eB = fmaf(b3, fa.w, eB);
            eB = fmaf(b4, fb.x, eB);
            float kA = EXP2F(eA);
            float kB = EXP2F(eB);
            float4 v0 = qv4[6*j+0], v1 = qv4[6*j+1], v2 = qv4[6*j+2];
            float4 v3 = qv4[6*j+3], v4 = qv4[6*j+4], v5 = qv4[6*j+5];
            fma4(accA[0], kA, v0); fma4(accA[1], kA, v1); fma4(accA[2], kA, v2);
            fma4(accA[3], kA, v3); fma4(accA[4], kA, v4); fma4(accA[5], kA, v5);
            fma4(accB[0], kB, v0); fma4(accB[1], kB, v1); fma4(accB[2], kB, v2);
            fma4(accB[3], kB, v3); fma4(accB[4], kB, v4); fma4(accB[5], kB, v5);
        }
        float4* oA = (float4*)(ws + OFF_PART) + ((s * NBATCH + n) * NP + p0) * 6;
        float4* oB = (float4*)(ws + OFF_PART) + ((s * NBATCH + n) * NP + p1) * 6;
        #pragma unroll
        for (int k = 0; k < 6; ++k) { oA[k] = accA[k]; oB[k] = accB[k]; }
    } else {
        // conv-y (zero pad), float4 over x
        int j = (b - nbBil) * 256 + tid;          // < NB*NC*H*16 = 43008
        if (j >= NBATCH * NC * HH * 16) return;
        int x4 = j & 15, yy = (j >> 4) & 63, nc = j >> 10;   // nc = n*21+c
        const float4* src = (const float4*)qplanar + nc * HH * 16;
        const float* g1 = ws + OFF_G1;
        float4 acc = make_float4(0.f, 0.f, 0.f, 0.f);
        for (int dy = 0; dy < KS; ++dy) {
            int ys = yy + dy - KR;
            if (ys >= 0 && ys < HH) {
                float g = g1[dy];
                float4 t = src[ys * 16 + x4];
                fma4(acc, g, t);
            }
        }
        ((float4*)(ws + OFF_TMP))[nc * HH * 16 + yy * 16 + x4] = acc;
    }
}

// blocks [0, nbRed): reduce partial slices into slice 0.  rest: conv-x.
__global__ __launch_bounds__(256) void reduce_convx_kernel(
    float* __restrict__ ws, int nbRed, int S)
{
    int b = blockIdx.x, tid = threadIdx.x;
    if (b < nbRed) {
        int j = b * 256 + tid;                 // < NB*P*6 = 49152
        const float4* part = (const float4*)(ws + OFF_PART);
        float4 acc = make_float4(0.f, 0.f, 0.f, 0.f);
        for (int s = 0; s < S; ++s) {
            float4 t = part[s * (NBATCH * NP * 6) + j];
            acc.x += t.x; acc.y += t.y; acc.z += t.z; acc.w += t.w;
        }
        ((float4*)(ws + OFF_PART))[j] = acc;   // reduced qbf lives in slice 0
    } else {
        int j2 = (b - nbRed) * 256 + tid;      // < NB*NC*P = 172032
        if (j2 >= NBATCH * NC * NP) return;
        int p = j2 & (NP - 1);
        int t = j2 >> 12;                      // n*21 + c
        int y = p >> 6, x = p & 63;
        const float* g1 = ws + OFF_G1;
        const float* trow = ws + OFF_TMP + t * NP + y * WW;
        int dlo = (x >= KR) ? 0 : (KR - x);
        int dhi = (x + KR <= WW - 1) ? (KS - 1) : (WW - 1 - x + KR);
        float qs = 0.f;
        for (int dx = dlo; dx <= dhi; ++dx)
            qs = fmaf(g1[dx], trow[x + dx - KR], qs);
        ws[OFF_QSF + j2] = qs;
    }
}

__global__ __launch_bounds__(256) void update_kernel(
    float* __restrict__ ws, float* __restrict__ outq)
{
    int gid = blockIdx.x * 256 + threadIdx.x;  // < NB*P = 8192
    int n = gid >> 12, p = gid & (NP - 1);
    const float4* qbf4 = (const float4*)(ws + OFF_PART) + (n * NP + p) * 6;
    float qb[NCP];
    #pragma unroll
    for (int k = 0; k < 6; ++k) {
        float4 t = qbf4[k];
        qb[4*k+0] = t.x; qb[4*k+1] = t.y; qb[4*k+2] = t.z; qb[4*k+3] = t.w;
    }
    const float* ut  = ws + OFF_UT  + gid * NCP;
    const float* qsf = ws + OFF_QSF + n * NC * NP + p;
    float l[NC], e[NC];
    float m = -1e30f;
    #pragma unroll
    for (int c = 0; c < NC; ++c) {
        float li = ut[c] + 4.0f * qb[c] + 2.0f * qsf[c * NP];
        l[c] = li;
        m = fmaxf(m, li);
    }
    float ssum = 0.f;
    #pragma unroll
    for (int c = 0; c < NC; ++c) { e[c] = EXP2F(L2E * (l[c] - m)); ssum += e[c]; }
    float inv = 1.0f / ssum;
    float* qt = ws + OFF_QT + gid * NCP;
    #pragma unroll
    for (int c = 0; c < NC; ++c) {
        float qv = e[c] * inv;
        qt[c] = qv;
        outq[(n * NC + c) * NP + p] = qv;     // planar q (final iter -> answer)
    }
    qt[21] = 0.f; qt[22] = 0.f; qt[23] = 0.f;
}

extern "C" void kernel_launch(void* const* d_in, const int* in_sizes, int n_in,
                              void* d_out, int out_size, void* d_ws, size_t ws_size,
                              hipStream_t stream)
{
    const float* unary = (const float*)d_in[0];
    const float* ref   = (const float*)d_in[1];
    // d_in[2] = gk (we rebuild its separable 1-D factor analytically)
    const float* kstd  = (const float*)d_in[3];
    float* ws   = (float*)d_ws;
    float* outq = (float*)d_out;

    // pick largest power-of-two q-split whose partial buffer fits the workspace
    size_t avail = ws_size / 4;
    int S = 1;
    for (int cand = 32; cand >= 1; cand >>= 1) {
        if ((size_t)OFF_PART + (size_t)cand * (NBATCH * NP * NCP) <= avail) { S = cand; break; }
    }
    int nbBil   = 16 * S;                              // 2 batches * 8 p-tiles * S
    int nbConvy = (NBATCH * NC * HH * 16 + 255) / 256; // 168
    int nbRed   = (NBATCH * NP * 6) / 256;             // 192
    int nbConvx = (NBATCH * NC * NP) / 256;            // 672

    setup_kernel<<<32, 256, 0, stream>>>(unary, ref, kstd, ws, outq);
    for (int it = 0; it < 5; ++it) {
        bilat_convy_kernel<<<nbBil + nbConvy, 256, 0, stream>>>(ws, outq, nbBil, S);
        reduce_convx_kernel<<<nbRed + nbConvx, 256, 0, stream>>>(ws, nbRed, S);
        update_kernel<<<32, 256, 0, stream>>>(ws, outq);
    }
}

// Round 2
// 431.165 us; speedup vs baseline: 1.6159x; 1.6159x over previous
//
#include <hip/hip_runtime.h>
#include <math.h>

#ifndef __has_builtin
#define __has_builtin(x) 0
#endif
#if __has_builtin(__builtin_amdgcn_exp2f)
#define EXP2F(x) __builtin_amdgcn_exp2f(x)
#else
#define EXP2F(x) exp2f(x)
#endif

#define L2E 1.44269504088896340736f

#define NBATCH 2
#define NC 21
#define NCP 24
#define HH 64
#define WW 64
#define NP 4096
#define KR 35
#define KS 71

// ws layout (float offsets); all 16B-aligned
#define OFF_FEATP 0         // [NB][P][8]  {f0..f4, h, 0, 0}   raw p-side feats
#define OFF_QREC  65536     // [NB][P][32] {L*f0..L*f4, h, 0,0, qv[21], 0,0,0}
#define OFF_UT    327680    // [NB][P][24] log-unary, transposed
#define OFF_TMP   524288    // [NB][NC][H][W] conv-y output
#define OFF_QSF   696320    // [NB][NC][H][W] conv-x output
#define OFF_G1    868352    // [71] 1-D gaussian (pad to 128)
#define OFF_PART  868480    // [S][NB][P][24] bilateral partials

#define PTILES 8            // 512 p per block, 2 per thread

static __device__ __forceinline__ void fma4(float4& a, float k, const float4& v) {
    a.x = fmaf(k, v.x, a.x);
    a.y = fmaf(k, v.y, a.y);
    a.z = fmaf(k, v.z, a.z);
    a.w = fmaf(k, v.w, a.w);
}

__global__ __launch_bounds__(256) void setup_kernel(
    const float* __restrict__ unary, const float* __restrict__ ref,
    const float* __restrict__ kstd, float* __restrict__ ws,
    float* __restrict__ outq)
{
    int gid = blockIdx.x * 256 + threadIdx.x;
    if (gid < KS) {
        float s = 0.f;
        for (int j = 0; j < KS; ++j) {
            float d = (float)(j - KR);
            s += expf(-d * d * (1.0f / 72.0f));
        }
        float d = (float)(gid - KR);
        ws[OFF_G1 + gid] = expf(-d * d * (1.0f / 72.0f)) / s;
    }
    if (gid >= NBATCH * NP) return;
    int n = gid >> 12, p = gid & (NP - 1);
    int y = p >> 6, x = p & 63;
    float k0 = kstd[0], k1 = kstd[1], k2 = kstd[2], k3 = kstd[3], k4 = kstd[4];
    const float* rp = ref + n * 3 * NP + p;
    float f0 = (float)y / k0;
    float f1 = (float)x / k1;
    float f2 = rp[0]      / k2;
    float f3 = rp[NP]     / k3;
    float f4 = rp[2 * NP] / k4;
    float sq = f0*f0 + f1*f1 + f2*f2 + f3*f3 + f4*f4;
    float h  = -0.5f * L2E * sq;   // exponent(p,q) = L*dot(fp,fq) + h_p + h_q
    float* fp = ws + OFF_FEATP + gid * 8;
    fp[0]=f0; fp[1]=f1; fp[2]=f2; fp[3]=f3; fp[4]=f4; fp[5]=h; fp[6]=0.f; fp[7]=0.f;
    float* qr = ws + OFF_QREC + gid * 32;
    qr[0]=L2E*f0; qr[1]=L2E*f1; qr[2]=L2E*f2; qr[3]=L2E*f3; qr[4]=L2E*f4;
    qr[5]=h; qr[6]=0.f; qr[7]=0.f;

    float U[NC], e[NC];
    const float* up = unary + n * NC * NP + p;
    float m = -1e30f;
    for (int c = 0; c < NC; ++c) {
        float u = up[c * NP];
        u = fminf(fmaxf(u, 1e-5f), 1.0f);
        U[c] = logf(u);
        m = fmaxf(m, U[c]);
    }
    float ssum = 0.f;
    for (int c = 0; c < NC; ++c) { e[c] = EXP2F(L2E * (U[c] - m)); ssum += e[c]; }
    float inv = 1.0f / ssum;
    float* ut = ws + OFF_UT + gid * NCP;
    for (int c = 0; c < NC; ++c) {
        float qv = e[c] * inv;
        ut[c] = U[c];
        qr[8 + c] = qv;
        outq[(n * NC + c) * NP + p] = qv;   // planar q0 (d_out doubles as buffer)
    }
    for (int c = NC; c < NCP; ++c) ut[c] = 0.f;
    qr[29] = 0.f; qr[30] = 0.f; qr[31] = 0.f;
}

// blocks [0, nbBil): bilateral partial sums.  blocks [nbBil, ...): conv-y.
__global__ __launch_bounds__(256) void bilat_convy_kernel(
    const float* __restrict__ featp,
    const float* __restrict__ qrec,     // uniform-indexed, read-only -> s_load
    const float* __restrict__ qplanar,
    const float* __restrict__ g1,
    float* __restrict__ part,
    float* __restrict__ tmp,
    int nbBil, int S)
{
    int b = blockIdx.x;
    int tid = threadIdx.x;
    if (b < nbBil) {
        int n  = b & 1;
        int pt = (b >> 1) & (PTILES - 1);
        int s  = b >> 4;
        int chunk = NP / S;
        int p0 = pt * 512 + tid;
        int p1 = p0 + 256;
        const float* fpA = featp + (n * NP + p0) * 8;
        const float* fpB = featp + (n * NP + p1) * 8;
        float a0=fpA[0], a1=fpA[1], a2=fpA[2], a3=fpA[3], a4=fpA[4], ah=fpA[5];
        float b0=fpB[0], b1=fpB[1], b2=fpB[2], b3=fpB[3], b4=fpB[4], bh=fpB[5];
        float accA[NCP], accB[NCP];
        #pragma unroll
        for (int k = 0; k < NCP; ++k) { accA[k] = 0.f; accB[k] = 0.f; }
        const float* rbase = qrec + (size_t)(n * NP + s * chunk) * 32;
        #pragma unroll 2
        for (int j = 0; j < chunk; ++j) {
            const float* r = rbase + j * 32;      // block-uniform address
            float q0 = r[0], q1 = r[1], q2 = r[2], q3 = r[3], q4 = r[4], qh = r[5];
            float eA = ah + qh;
            eA = fmaf(a0, q0, eA); eA = fmaf(a1, q1, eA);
            eA = fmaf(a2, q2, eA); eA = fmaf(a3, q3, eA);
            eA = fmaf(a4, q4, eA);
            float eB = bh + qh;
            eB = fmaf(b0, q0, eB); eB = fmaf(b1, q1, eB);
            eB = fmaf(b2, q2, eB); eB = fmaf(b3, q3, eB);
            eB = fmaf(b4, q4, eB);
            float kA = EXP2F(eA);
            float kB = EXP2F(eB);
            #pragma unroll
            for (int c = 0; c < NC; ++c) {
                float qv = r[8 + c];              // SGPR operand in v_fmac
                accA[c] = fmaf(kA, qv, accA[c]);
                accB[c] = fmaf(kB, qv, accB[c]);
            }
        }
        float4* oA = (float4*)(part + ((size_t)(s * NBATCH + n) * NP + p0) * 24);
        float4* oB = (float4*)(part + ((size_t)(s * NBATCH + n) * NP + p1) * 24);
        #pragma unroll
        for (int k = 0; k < 6; ++k) {
            oA[k] = make_float4(accA[4*k], accA[4*k+1], accA[4*k+2], accA[4*k+3]);
            oB[k] = make_float4(accB[4*k], accB[4*k+1], accB[4*k+2], accB[4*k+3]);
        }
    } else {
        // conv-y (zero pad), float4 over x
        int j = (b - nbBil) * 256 + tid;          // < NB*NC*H*16 = 43008
        if (j >= NBATCH * NC * HH * 16) return;
        int x4 = j & 15, yy = (j >> 4) & 63, nc = j >> 10;   // nc = n*21+c
        const float4* src = (const float4*)qplanar + nc * HH * 16;
        float4 acc = make_float4(0.f, 0.f, 0.f, 0.f);
        for (int dy = 0; dy < KS; ++dy) {
            int ys = yy + dy - KR;
            if (ys >= 0 && ys < HH) {
                float g = g1[dy];
                float4 t = src[ys * 16 + x4];
                fma4(acc, g, t);
            }
        }
        ((float4*)tmp)[nc * HH * 16 + yy * 16 + x4] = acc;
    }
}

// blocks [0, nbRed): reduce partial slices into slice 0.  rest: conv-x.
__global__ __launch_bounds__(256) void reduce_convx_kernel(
    float* __restrict__ ws, int nbRed, int S)
{
    int b = blockIdx.x, tid = threadIdx.x;
    if (b < nbRed) {
        int j = b * 256 + tid;                 // < NB*P*6 = 49152
        const float4* part = (const float4*)(ws + OFF_PART);
        float4 acc = make_float4(0.f, 0.f, 0.f, 0.f);
        for (int s = 0; s < S; ++s) {
            float4 t = part[s * (NBATCH * NP * 6) + j];
            acc.x += t.x; acc.y += t.y; acc.z += t.z; acc.w += t.w;
        }
        ((float4*)(ws + OFF_PART))[j] = acc;   // reduced qbf lives in slice 0
    } else {
        int j2 = (b - nbRed) * 256 + tid;      // < NB*NC*P = 172032
        if (j2 >= NBATCH * NC * NP) return;
        int p = j2 & (NP - 1);
        int t = j2 >> 12;                      // n*21 + c
        int y = p >> 6, x = p & 63;
        const float* g1 = ws + OFF_G1;
        const float* trow = ws + OFF_TMP + t * NP + y * WW;
        int dlo = (x >= KR) ? 0 : (KR - x);
        int dhi = (x + KR <= WW - 1) ? (KS - 1) : (WW - 1 - x + KR);
        float qs = 0.f;
        for (int dx = dlo; dx <= dhi; ++dx)
            qs = fmaf(g1[dx], trow[x + dx - KR], qs);
        ws[OFF_QSF + j2] = qs;
    }
}

__global__ __launch_bounds__(256) void update_kernel(
    float* __restrict__ ws, float* __restrict__ outq)
{
    int gid = blockIdx.x * 256 + threadIdx.x;  // < NB*P = 8192
    int n = gid >> 12, p = gid & (NP - 1);
    const float4* qbf4 = (const float4*)(ws + OFF_PART) + (n * NP + p) * 6;
    float qb[NCP];
    #pragma unroll
    for (int k = 0; k < 6; ++k) {
        float4 t = qbf4[k];
        qb[4*k+0] = t.x; qb[4*k+1] = t.y; qb[4*k+2] = t.z; qb[4*k+3] = t.w;
    }
    const float* ut  = ws + OFF_UT  + gid * NCP;
    const float* qsf = ws + OFF_QSF + n * NC * NP + p;
    float l[NC], e[NC];
    float m = -1e30f;
    #pragma unroll
    for (int c = 0; c < NC; ++c) {
        float li = ut[c] + 4.0f * qb[c] + 2.0f * qsf[c * NP];
        l[c] = li;
        m = fmaxf(m, li);
    }
    float ssum = 0.f;
    #pragma unroll
    for (int c = 0; c < NC; ++c) { e[c] = EXP2F(L2E * (l[c] - m)); ssum += e[c]; }
    float inv = 1.0f / ssum;
    float* qr = ws + OFF_QREC + gid * 32;
    #pragma unroll
    for (int c = 0; c < NC; ++c) {
        float qv = e[c] * inv;
        qr[8 + c] = qv;
        outq[(n * NC + c) * NP + p] = qv;     // planar q (final iter -> answer)
    }
    qr[29] = 0.f; qr[30] = 0.f; qr[31] = 0.f;
}

extern "C" void kernel_launch(void* const* d_in, const int* in_sizes, int n_in,
                              void* d_out, int out_size, void* d_ws, size_t ws_size,
                              hipStream_t stream)
{
    const float* unary = (const float*)d_in[0];
    const float* ref   = (const float*)d_in[1];
    const float* kstd  = (const float*)d_in[3];
    float* ws   = (float*)d_ws;
    float* outq = (float*)d_out;

    size_t avail = ws_size / 4;
    int S = 1;
    for (int cand = 32; cand >= 1; cand >>= 1) {
        if ((size_t)OFF_PART + (size_t)cand * (NBATCH * NP * NCP) <= avail) { S = cand; break; }
    }
    int nbBil   = 16 * S;                              // 512 @ S=32
    int nbConvy = (NBATCH * NC * HH * 16 + 255) / 256; // 168
    int nbRed   = (NBATCH * NP * 6) / 256;             // 192
    int nbConvx = (NBATCH * NC * NP) / 256;            // 672

    float* featp = ws + OFF_FEATP;
    float* qrec  = ws + OFF_QREC;
    float* g1    = ws + OFF_G1;
    float* part  = ws + OFF_PART;
    float* tmp   = ws + OFF_TMP;

    setup_kernel<<<32, 256, 0, stream>>>(unary, ref, kstd, ws, outq);
    for (int it = 0; it < 5; ++it) {
        bilat_convy_kernel<<<nbBil + nbConvy, 256, 0, stream>>>(
            featp, qrec, outq, g1, part, tmp, nbBil, S);
        reduce_convx_kernel<<<nbRed + nbConvx, 256, 0, stream>>>(ws, nbRed, S);
        update_kernel<<<32, 256, 0, stream>>>(ws, outq);
    }
}

// Round 3
// 382.952 us; speedup vs baseline: 1.8194x; 1.1259x over previous
//
#include <hip/hip_runtime.h>
#include <math.h>

#ifndef __has_builtin
#define __has_builtin(x) 0
#endif
#if __has_builtin(__builtin_amdgcn_exp2f)
#define EXP2F(x) __builtin_amdgcn_exp2f(x)
#else
#define EXP2F(x) exp2f(x)
#endif

#define L2E 1.44269504088896340736f

#define NBATCH 2
#define NC 21
#define NCP 24
#define HH 64
#define WW 64
#define NP 4096
#define KR 35
#define KS 71

// ws layout (float offsets); all 16B-aligned
#define OFF_FEATP 0         // [NB][P][8]  {f0..f4, h, 0, 0}   raw p-side feats
#define OFF_QREC  65536     // [NB][P][32] {L*f0..L*f4, h, 0,0, qv[21], 0,0,0}
#define OFF_UT    327680    // [NB][P][24] log-unary, transposed
#define OFF_TMP   524288    // [NB][NC][H][W] conv-y output
#define OFF_QSF   696320    // [NB][NC][H][W] conv-x output
#define OFF_G1    868352    // [71] 1-D gaussian (pad to 128)
#define OFF_PART  868480    // [S][NB][P][24] bilateral partials

#define PTILES 8            // 512 p per block, 2 per thread

static __device__ __forceinline__ void fma4(float4& a, float k, const float4& v) {
    a.x = fmaf(k, v.x, a.x);
    a.y = fmaf(k, v.y, a.y);
    a.z = fmaf(k, v.z, a.z);
    a.w = fmaf(k, v.w, a.w);
}

__global__ __launch_bounds__(256) void setup_kernel(
    const float* __restrict__ unary, const float* __restrict__ ref,
    const float* __restrict__ kstd, float* __restrict__ ws,
    float* __restrict__ outq)
{
    int gid = blockIdx.x * 256 + threadIdx.x;
    if (gid < KS) {
        float s = 0.f;
        for (int j = 0; j < KS; ++j) {
            float d = (float)(j - KR);
            s += expf(-d * d * (1.0f / 72.0f));
        }
        float d = (float)(gid - KR);
        ws[OFF_G1 + gid] = expf(-d * d * (1.0f / 72.0f)) / s;
    }
    if (gid >= NBATCH * NP) return;
    int n = gid >> 12, p = gid & (NP - 1);
    int y = p >> 6, x = p & 63;
    float k0 = kstd[0], k1 = kstd[1], k2 = kstd[2], k3 = kstd[3], k4 = kstd[4];
    const float* rp = ref + n * 3 * NP + p;
    float f0 = (float)y / k0;
    float f1 = (float)x / k1;
    float f2 = rp[0]      / k2;
    float f3 = rp[NP]     / k3;
    float f4 = rp[2 * NP] / k4;
    float sq = f0*f0 + f1*f1 + f2*f2 + f3*f3 + f4*f4;
    float h  = -0.5f * L2E * sq;   // exponent(p,q) = L*dot(fp,fq) + h_p + h_q
    float* fp = ws + OFF_FEATP + gid * 8;
    fp[0]=f0; fp[1]=f1; fp[2]=f2; fp[3]=f3; fp[4]=f4; fp[5]=h; fp[6]=0.f; fp[7]=0.f;
    float* qr = ws + OFF_QREC + gid * 32;
    qr[0]=L2E*f0; qr[1]=L2E*f1; qr[2]=L2E*f2; qr[3]=L2E*f3; qr[4]=L2E*f4;
    qr[5]=h; qr[6]=0.f; qr[7]=0.f;

    float U[NC], e[NC];
    const float* up = unary + n * NC * NP + p;
    float m = -1e30f;
    for (int c = 0; c < NC; ++c) {
        float u = up[c * NP];
        u = fminf(fmaxf(u, 1e-5f), 1.0f);
        U[c] = logf(u);
        m = fmaxf(m, U[c]);
    }
    float ssum = 0.f;
    for (int c = 0; c < NC; ++c) { e[c] = EXP2F(L2E * (U[c] - m)); ssum += e[c]; }
    float inv = 1.0f / ssum;
    float* ut = ws + OFF_UT + gid * NCP;
    for (int c = 0; c < NC; ++c) {
        float qv = e[c] * inv;
        ut[c] = U[c];
        qr[8 + c] = qv;
        outq[(n * NC + c) * NP + p] = qv;   // planar q0 (d_out doubles as buffer)
    }
    for (int c = NC; c < NCP; ++c) ut[c] = 0.f;
    qr[29] = 0.f; qr[30] = 0.f; qr[31] = 0.f;
}

// blocks [0, nbBil): bilateral partial sums.  blocks [nbBil, ...): conv-y.
__global__ __launch_bounds__(256) void bilat_convy_kernel(
    const float* __restrict__ featp,
    const float* __restrict__ qrec,
    const float* __restrict__ qplanar,
    const float* __restrict__ g1,
    float* __restrict__ part,
    float* __restrict__ tmp,
    int nbBil, int S)
{
    __shared__ float lds_q[4096];   // up to 128 q-records * 32 floats = 16 KB
    int b = blockIdx.x;
    int tid = threadIdx.x;
    if (b < nbBil) {
        int n  = b & 1;
        int pt = (b >> 1) & (PTILES - 1);
        int s  = b >> 4;
        int chunk = NP / S;
        int p0 = pt * 512 + tid;
        int p1 = p0 + 256;

        // stage this block's q-slice into LDS (coalesced float4)
        {
            int nfl4 = chunk * 8;   // chunk*32 floats / 4
            const float4* src = (const float4*)qrec + (size_t)(n * NP + s * chunk) * 8;
            float4* dst = (float4*)lds_q;
            for (int k = tid; k < nfl4; k += 256) dst[k] = src[k];
        }

        const float* fpA = featp + (n * NP + p0) * 8;
        const float* fpB = featp + (n * NP + p1) * 8;
        float a0=fpA[0], a1=fpA[1], a2=fpA[2], a3=fpA[3], a4=fpA[4], ah=fpA[5];
        float b0=fpB[0], b1=fpB[1], b2=fpB[2], b3=fpB[3], b4=fpB[4], bh=fpB[5];
        float accA[NCP], accB[NCP];
        #pragma unroll
        for (int k = 0; k < NCP; ++k) { accA[k] = 0.f; accB[k] = 0.f; }

        __syncthreads();

        #pragma unroll 2
        for (int j = 0; j < chunk; ++j) {
            const float* r = lds_q + j * 32;   // wave-uniform -> LDS broadcast
            float q0 = r[0], q1 = r[1], q2 = r[2], q3 = r[3], q4 = r[4], qh = r[5];
            float eA = ah + qh;
            eA = fmaf(a0, q0, eA); eA = fmaf(a1, q1, eA);
            eA = fmaf(a2, q2, eA); eA = fmaf(a3, q3, eA);
            eA = fmaf(a4, q4, eA);
            float eB = bh + qh;
            eB = fmaf(b0, q0, eB); eB = fmaf(b1, q1, eB);
            eB = fmaf(b2, q2, eB); eB = fmaf(b3, q3, eB);
            eB = fmaf(b4, q4, eB);
            float kA = EXP2F(eA);
            float kB = EXP2F(eB);
            #pragma unroll
            for (int c = 0; c < NC; ++c) {
                float qv = r[8 + c];
                accA[c] = fmaf(kA, qv, accA[c]);
                accB[c] = fmaf(kB, qv, accB[c]);
            }
        }
        float4* oA = (float4*)(part + ((size_t)(s * NBATCH + n) * NP + p0) * 24);
        float4* oB = (float4*)(part + ((size_t)(s * NBATCH + n) * NP + p1) * 24);
        #pragma unroll
        for (int k = 0; k < 6; ++k) {
            oA[k] = make_float4(accA[4*k], accA[4*k+1], accA[4*k+2], accA[4*k+3]);
            oB[k] = make_float4(accB[4*k], accB[4*k+1], accB[4*k+2], accB[4*k+3]);
        }
    } else {
        // conv-y (zero pad), float4 over x
        int j = (b - nbBil) * 256 + tid;          // < NB*NC*H*16 = 43008
        if (j >= NBATCH * NC * HH * 16) return;
        int x4 = j & 15, yy = (j >> 4) & 63, nc = j >> 10;   // nc = n*21+c
        const float4* src = (const float4*)qplanar + nc * HH * 16;
        float4 acc = make_float4(0.f, 0.f, 0.f, 0.f);
        for (int dy = 0; dy < KS; ++dy) {
            int ys = yy + dy - KR;
            if (ys >= 0 && ys < HH) {
                float g = g1[dy];
                float4 t = src[ys * 16 + x4];
                fma4(acc, g, t);
            }
        }
        ((float4*)tmp)[nc * HH * 16 + yy * 16 + x4] = acc;
    }
}

// blocks [0, nbRed): reduce partial slices into slice 0.  rest: conv-x.
__global__ __launch_bounds__(256) void reduce_convx_kernel(
    float* __restrict__ ws, int nbRed, int S)
{
    int b = blockIdx.x, tid = threadIdx.x;
    if (b < nbRed) {
        int j = b * 256 + tid;                 // < NB*P*6 = 49152
        const float4* part = (const float4*)(ws + OFF_PART);
        float4 acc = make_float4(0.f, 0.f, 0.f, 0.f);
        for (int s = 0; s < S; ++s) {
            float4 t = part[s * (NBATCH * NP * 6) + j];
            acc.x += t.x; acc.y += t.y; acc.z += t.z; acc.w += t.w;
        }
        ((float4*)(ws + OFF_PART))[j] = acc;   // reduced qbf lives in slice 0
    } else {
        int j2 = (b - nbRed) * 256 + tid;      // < NB*NC*P = 172032
        if (j2 >= NBATCH * NC * NP) return;
        int p = j2 & (NP - 1);
        int t = j2 >> 12;                      // n*21 + c
        int y = p >> 6, x = p & 63;
        const float* g1 = ws + OFF_G1;
        const float* trow = ws + OFF_TMP + t * NP + y * WW;
        int dlo = (x >= KR) ? 0 : (KR - x);
        int dhi = (x + KR <= WW - 1) ? (KS - 1) : (WW - 1 - x + KR);
        float qs = 0.f;
        for (int dx = dlo; dx <= dhi; ++dx)
            qs = fmaf(g1[dx], trow[x + dx - KR], qs);
        ws[OFF_QSF + j2] = qs;
    }
}

__global__ __launch_bounds__(256) void update_kernel(
    float* __restrict__ ws, float* __restrict__ outq)
{
    int gid = blockIdx.x * 256 + threadIdx.x;  // < NB*P = 8192
    int n = gid >> 12, p = gid & (NP - 1);
    const float4* qbf4 = (const float4*)(ws + OFF_PART) + (n * NP + p) * 6;
    float qb[NCP];
    #pragma unroll
    for (int k = 0; k < 6; ++k) {
        float4 t = qbf4[k];
        qb[4*k+0] = t.x; qb[4*k+1] = t.y; qb[4*k+2] = t.z; qb[4*k+3] = t.w;
    }
    const float* ut  = ws + OFF_UT  + gid * NCP;
    const float* qsf = ws + OFF_QSF + n * NC * NP + p;
    float l[NC], e[NC];
    float m = -1e30f;
    #pragma unroll
    for (int c = 0; c < NC; ++c) {
        float li = ut[c] + 4.0f * qb[c] + 2.0f * qsf[c * NP];
        l[c] = li;
        m = fmaxf(m, li);
    }
    float ssum = 0.f;
    #pragma unroll
    for (int c = 0; c < NC; ++c) { e[c] = EXP2F(L2E * (l[c] - m)); ssum += e[c]; }
    float inv = 1.0f / ssum;
    float* qr = ws + OFF_QREC + gid * 32;
    #pragma unroll
    for (int c = 0; c < NC; ++c) {
        float qv = e[c] * inv;
        qr[8 + c] = qv;
        outq[(n * NC + c) * NP + p] = qv;     // planar q (final iter -> answer)
    }
    qr[29] = 0.f; qr[30] = 0.f; qr[31] = 0.f;
}

extern "C" void kernel_launch(void* const* d_in, const int* in_sizes, int n_in,
                              void* d_out, int out_size, void* d_ws, size_t ws_size,
                              hipStream_t stream)
{
    const float* unary = (const float*)d_in[0];
    const float* ref   = (const float*)d_in[1];
    const float* kstd  = (const float*)d_in[3];
    float* ws   = (float*)d_ws;
    float* outq = (float*)d_out;

    // largest power-of-two q-split whose partial buffer fits the workspace
    size_t avail = ws_size / 4;
    int S = 1;
    for (int cand = 64; cand >= 1; cand >>= 1) {
        if ((size_t)OFF_PART + (size_t)cand * (NBATCH * NP * NCP) <= avail) { S = cand; break; }
    }
    int nbBil   = 16 * S;                              // 1024 @ S=64
    int nbConvy = (NBATCH * NC * HH * 16 + 255) / 256; // 168
    int nbRed   = (NBATCH * NP * 6) / 256;             // 192
    int nbConvx = (NBATCH * NC * NP) / 256;            // 672

    float* featp = ws + OFF_FEATP;
    float* qrec  = ws + OFF_QREC;
    float* g1    = ws + OFF_G1;
    float* part  = ws + OFF_PART;
    float* tmp   = ws + OFF_TMP;

    setup_kernel<<<32, 256, 0, stream>>>(unary, ref, kstd, ws, outq);
    for (int it = 0; it < 5; ++it) {
        bilat_convy_kernel<<<nbBil + nbConvy, 256, 0, stream>>>(
            featp, qrec, outq, g1, part, tmp, nbBil, S);
        reduce_convx_kernel<<<nbRed + nbConvx, 256, 0, stream>>>(ws, nbRed, S);
        update_kernel<<<32, 256, 0, stream>>>(ws, outq);
    }
}

// Round 4
// 369.900 us; speedup vs baseline: 1.8836x; 1.0353x over previous
//
#include <hip/hip_runtime.h>
#include <hip/hip_fp16.h>
#include <math.h>

#ifndef __has_builtin
#define __has_builtin(x) 0
#endif
#if __has_builtin(__builtin_amdgcn_exp2f)
#define EXP2F(x) __builtin_amdgcn_exp2f(x)
#else
#define EXP2F(x) exp2f(x)
#endif

#define L2E 1.44269504088896340736f

#define NBATCH 2
#define NC 21
#define NCP 24
#define HH 64
#define WW 64
#define NP 4096
#define KR 35
#define KS 71

// ws layout (float offsets); all 16B-aligned
#define OFF_FEATP 0         // [NB][P][8]  {f0..f4, h, 0, 0}
#define OFF_QREC  65536     // [NB][P][32] {L*f0..L*f4, h, 0,0, qv[21], 0,0,0}
#define OFF_UT    327680    // [NB][P][24] log-unary, transposed
#define OFF_TMP   524288    // [NB][NC][H][W] conv-y output
#define OFF_QSF   696320    // [NB][NC][H][W] conv-x output
#define OFF_G1    868352    // [71] 1-D gaussian (pad to 128)
#define OFF_QBF   868480    // [NB][P][24] fp32 reduced bilateral
#define OFF_PART  1065088   // [S][NB][P][24] fp16 partials (half region)

#define PTILES 4            // 1024 p per block, 4 per thread

static __device__ __forceinline__ void fma4(float4& a, float k, const float4& v) {
    a.x = fmaf(k, v.x, a.x);
    a.y = fmaf(k, v.y, a.y);
    a.z = fmaf(k, v.z, a.z);
    a.w = fmaf(k, v.w, a.w);
}

__global__ __launch_bounds__(256) void setup_kernel(
    const float* __restrict__ unary, const float* __restrict__ ref,
    const float* __restrict__ kstd, float* __restrict__ ws,
    float* __restrict__ outq)
{
    int gid = blockIdx.x * 256 + threadIdx.x;
    if (gid < KS) {
        float s = 0.f;
        for (int j = 0; j < KS; ++j) {
            float d = (float)(j - KR);
            s += expf(-d * d * (1.0f / 72.0f));
        }
        float d = (float)(gid - KR);
        ws[OFF_G1 + gid] = expf(-d * d * (1.0f / 72.0f)) / s;
    }
    if (gid >= NBATCH * NP) return;
    int n = gid >> 12, p = gid & (NP - 1);
    int y = p >> 6, x = p & 63;
    float k0 = kstd[0], k1 = kstd[1], k2 = kstd[2], k3 = kstd[3], k4 = kstd[4];
    const float* rp = ref + n * 3 * NP + p;
    float f0 = (float)y / k0;
    float f1 = (float)x / k1;
    float f2 = rp[0]      / k2;
    float f3 = rp[NP]     / k3;
    float f4 = rp[2 * NP] / k4;
    float sq = f0*f0 + f1*f1 + f2*f2 + f3*f3 + f4*f4;
    float h  = -0.5f * L2E * sq;   // exponent(p,q) = L*dot(fp,fq) + h_p + h_q
    float* fp = ws + OFF_FEATP + gid * 8;
    fp[0]=f0; fp[1]=f1; fp[2]=f2; fp[3]=f3; fp[4]=f4; fp[5]=h; fp[6]=0.f; fp[7]=0.f;
    float* qr = ws + OFF_QREC + gid * 32;
    qr[0]=L2E*f0; qr[1]=L2E*f1; qr[2]=L2E*f2; qr[3]=L2E*f3; qr[4]=L2E*f4;
    qr[5]=h; qr[6]=0.f; qr[7]=0.f;

    float U[NC], e[NC];
    const float* up = unary + n * NC * NP + p;
    float m = -1e30f;
    for (int c = 0; c < NC; ++c) {
        float u = up[c * NP];
        u = fminf(fmaxf(u, 1e-5f), 1.0f);
        U[c] = logf(u);
        m = fmaxf(m, U[c]);
    }
    float ssum = 0.f;
    for (int c = 0; c < NC; ++c) { e[c] = EXP2F(L2E * (U[c] - m)); ssum += e[c]; }
    float inv = 1.0f / ssum;
    float* ut = ws + OFF_UT + gid * NCP;
    for (int c = 0; c < NC; ++c) {
        float qv = e[c] * inv;
        ut[c] = U[c];
        qr[8 + c] = qv;
        outq[(n * NC + c) * NP + p] = qv;   // planar q0 (d_out doubles as buffer)
    }
    for (int c = NC; c < NCP; ++c) ut[c] = 0.f;
    qr[29] = 0.f; qr[30] = 0.f; qr[31] = 0.f;
}

// blocks [0, nbBil): bilateral partials (fp16).  blocks [nbBil,...): conv-y.
__global__ __launch_bounds__(256, 2) void bilat_convy_kernel(
    const float* __restrict__ featp,
    const float* __restrict__ qrec,
    const float* __restrict__ qplanar,
    const float* __restrict__ g1,
    __half* __restrict__ part,
    float* __restrict__ tmp,
    int nbBil, int S)
{
    __shared__ float lds_q[2048];   // chunk(<=64) q-records * 32 floats
    int b = blockIdx.x;
    int tid = threadIdx.x;
    if (b < nbBil) {
        int n  = b & 1;
        int pt = (b >> 1) & (PTILES - 1);
        int s  = b >> 3;
        int chunk = NP / S;
        int p0 = pt * 1024 + tid;

        // stage this block's q-slice into LDS (coalesced float4)
        {
            int nfl4 = chunk * 8;
            const float4* src = (const float4*)qrec + (size_t)(n * NP + s * chunk) * 8;
            float4* dst = (float4*)lds_q;
            for (int k = tid; k < nfl4; k += 256) dst[k] = src[k];
        }

        float pf[4][6];
        #pragma unroll
        for (int t = 0; t < 4; ++t) {
            const float* fp = featp + (size_t)(n * NP + p0 + t * 256) * 8;
            #pragma unroll
            for (int k = 0; k < 6; ++k) pf[t][k] = fp[k];
        }
        float acc[4][NC];
        #pragma unroll
        for (int t = 0; t < 4; ++t)
            #pragma unroll
            for (int c = 0; c < NC; ++c) acc[t][c] = 0.f;

        __syncthreads();

        #pragma unroll 2
        for (int j = 0; j < chunk; ++j) {
            const float* r = lds_q + j * 32;   // wave-uniform -> LDS broadcast
            float q0 = r[0], q1 = r[1], q2 = r[2], q3 = r[3], q4 = r[4], qh = r[5];
            float kk[4];
            #pragma unroll
            for (int t = 0; t < 4; ++t) {
                float e = pf[t][5] + qh;
                e = fmaf(pf[t][0], q0, e); e = fmaf(pf[t][1], q1, e);
                e = fmaf(pf[t][2], q2, e); e = fmaf(pf[t][3], q3, e);
                e = fmaf(pf[t][4], q4, e);
                kk[t] = EXP2F(e);
            }
            #pragma unroll
            for (int c = 0; c < NC; ++c) {
                float qv = r[8 + c];
                acc[0][c] = fmaf(kk[0], qv, acc[0][c]);
                acc[1][c] = fmaf(kk[1], qv, acc[1][c]);
                acc[2][c] = fmaf(kk[2], qv, acc[2][c]);
                acc[3][c] = fmaf(kk[3], qv, acc[3][c]);
            }
        }
        #pragma unroll
        for (int t = 0; t < 4; ++t) {
            __half hb[24];
            #pragma unroll
            for (int c = 0; c < NC; ++c) hb[c] = __float2half(acc[t][c]);
            hb[21] = __float2half(0.f); hb[22] = hb[21]; hb[23] = hb[21];
            uint4* dst = (uint4*)part + ((size_t)(s * NBATCH + n) * NP + p0 + t * 256) * 3;
            const uint4* sv = (const uint4*)hb;
            dst[0] = sv[0]; dst[1] = sv[1]; dst[2] = sv[2];
        }
    } else {
        // conv-y (zero pad), float4 over x
        int j = (b - nbBil) * 256 + tid;          // < NB*NC*H*16 = 43008
        if (j >= NBATCH * NC * HH * 16) return;
        int x4 = j & 15, yy = (j >> 4) & 63, nc = j >> 10;
        const float4* src = (const float4*)qplanar + nc * HH * 16;
        float4 acc = make_float4(0.f, 0.f, 0.f, 0.f);
        for (int dy = 0; dy < KS; ++dy) {
            int ys = yy + dy - KR;
            if (ys >= 0 && ys < HH) {
                float g = g1[dy];
                float4 t = src[ys * 16 + x4];
                fma4(acc, g, t);
            }
        }
        ((float4*)tmp)[nc * HH * 16 + yy * 16 + x4] = acc;
    }
}

// blocks [0, nbRed): fp16 partials -> fp32 qbf.  rest: conv-x.
__global__ __launch_bounds__(256) void reduce_convx_kernel(
    float* __restrict__ ws, int nbRed, int S)
{
    int b = blockIdx.x, tid = threadIdx.x;
    if (b < nbRed) {
        int j = b * 256 + tid;                 // < NB*P*3 = 24576 (uint4 of 8 halves)
        const uint4* p4 = (const uint4*)(ws + OFF_PART);
        float a0=0.f,a1=0.f,a2=0.f,a3=0.f,a4=0.f,a5=0.f,a6=0.f,a7=0.f;
        for (int s = 0; s < S; ++s) {
            uint4 t = p4[(size_t)s * 24576 + j];
            const __half2* h2 = (const __half2*)&t;
            float2 f0 = __half22float2(h2[0]);
            float2 f1 = __half22float2(h2[1]);
            float2 f2 = __half22float2(h2[2]);
            float2 f3 = __half22float2(h2[3]);
            a0 += f0.x; a1 += f0.y; a2 += f1.x; a3 += f1.y;
            a4 += f2.x; a5 += f2.y; a6 += f3.x; a7 += f3.y;
        }
        float4* out = (float4*)(ws + OFF_QBF);
        out[j * 2]     = make_float4(a0, a1, a2, a3);
        out[j * 2 + 1] = make_float4(a4, a5, a6, a7);
    } else {
        int j2 = (b - nbRed) * 256 + tid;      // < NB*NC*P = 172032
        if (j2 >= NBATCH * NC * NP) return;
        int p = j2 & (NP - 1);
        int t = j2 >> 12;                      // n*21 + c
        int y = p >> 6, x = p & 63;
        const float* g1 = ws + OFF_G1;
        const float* trow = ws + OFF_TMP + t * NP + y * WW;
        int dlo = (x >= KR) ? 0 : (KR - x);
        int dhi = (x + KR <= WW - 1) ? (KS - 1) : (WW - 1 - x + KR);
        float qs = 0.f;
        for (int dx = dlo; dx <= dhi; ++dx)
            qs = fmaf(g1[dx], trow[x + dx - KR], qs);
        ws[OFF_QSF + j2] = qs;
    }
}

__global__ __launch_bounds__(256) void update_kernel(
    float* __restrict__ ws, float* __restrict__ outq)
{
    int gid = blockIdx.x * 256 + threadIdx.x;  // < NB*P = 8192
    int n = gid >> 12, p = gid & (NP - 1);
    const float4* qbf4 = (const float4*)(ws + OFF_QBF) + gid * 6;
    float qb[NCP];
    #pragma unroll
    for (int k = 0; k < 6; ++k) {
        float4 t = qbf4[k];
        qb[4*k+0] = t.x; qb[4*k+1] = t.y; qb[4*k+2] = t.z; qb[4*k+3] = t.w;
    }
    const float* ut  = ws + OFF_UT  + gid * NCP;
    const float* qsf = ws + OFF_QSF + n * NC * NP + p;
    float l[NC], e[NC];
    float m = -1e30f;
    #pragma unroll
    for (int c = 0; c < NC; ++c) {
        float li = ut[c] + 4.0f * qb[c] + 2.0f * qsf[c * NP];
        l[c] = li;
        m = fmaxf(m, li);
    }
    float ssum = 0.f;
    #pragma unroll
    for (int c = 0; c < NC; ++c) { e[c] = EXP2F(L2E * (l[c] - m)); ssum += e[c]; }
    float inv = 1.0f / ssum;
    float* qr = ws + OFF_QREC + gid * 32;
    #pragma unroll
    for (int c = 0; c < NC; ++c) {
        float qv = e[c] * inv;
        qr[8 + c] = qv;
        outq[(n * NC + c) * NP + p] = qv;     // planar q (final iter -> answer)
    }
    qr[29] = 0.f; qr[30] = 0.f; qr[31] = 0.f;
}

extern "C" void kernel_launch(void* const* d_in, const int* in_sizes, int n_in,
                              void* d_out, int out_size, void* d_ws, size_t ws_size,
                              hipStream_t stream)
{
    const float* unary = (const float*)d_in[0];
    const float* ref   = (const float*)d_in[1];
    const float* kstd  = (const float*)d_in[3];
    float* ws   = (float*)d_ws;
    float* outq = (float*)d_out;

    // largest power-of-two q-split whose fp16 partial buffer fits
    size_t avail = ws_size / 4;
    int S = 1;
    for (int cand = 64; cand >= 1; cand >>= 1) {
        if ((size_t)OFF_PART + (size_t)cand * (NBATCH * NP * NCP / 2) <= avail) { S = cand; break; }
    }
    int nbBil   = 2 * PTILES * S;                      // 512 @ S=64
    int nbConvy = (NBATCH * NC * HH * 16 + 255) / 256; // 168
    int nbRed   = (NBATCH * NP * 3) / 256;             // 96
    int nbConvx = (NBATCH * NC * NP) / 256;            // 672

    float*  featp = ws + OFF_FEATP;
    float*  qrec  = ws + OFF_QREC;
    float*  g1    = ws + OFF_G1;
    __half* part  = (__half*)(ws + OFF_PART);
    float*  tmp   = ws + OFF_TMP;

    setup_kernel<<<32, 256, 0, stream>>>(unary, ref, kstd, ws, outq);
    for (int it = 0; it < 5; ++it) {
        bilat_convy_kernel<<<nbBil + nbConvy, 256, 0, stream>>>(
            featp, qrec, outq, g1, part, tmp, nbBil, S);
        reduce_convx_kernel<<<nbRed + nbConvx, 256, 0, stream>>>(ws, nbRed, S);
        update_kernel<<<32, 256, 0, stream>>>(ws, outq);
    }
}

// Round 5
// 190.958 us; speedup vs baseline: 3.6486x; 1.9371x over previous
//
#include <hip/hip_runtime.h>
#include <math.h>

#ifndef __has_builtin
#define __has_builtin(x) 0
#endif
#if __has_builtin(__builtin_amdgcn_exp2f)
#define EXP2F(x) __builtin_amdgcn_exp2f(x)
#else
#define EXP2F(x) exp2f(x)
#endif

#define L2E  1.44269504088896340736f
#define RL2E 0.69314718055994530942f

#define NBATCH 2
#define NC 21
#define HH 64
#define WW 64
#define NP 4096
#define KR 35
#define KS 71

typedef _Float16 half_t;
typedef _Float16 h8 __attribute__((ext_vector_type(8)));
typedef _Float16 h4 __attribute__((ext_vector_type(4)));
typedef float f4 __attribute__((ext_vector_type(4)));
#define MFMA16(a, b, c) __builtin_amdgcn_mfma_f32_16x16x32_f16((a), (b), (c), 0, 0, 0)

// ---- tiling ----
#define PTILE 256          // p per bilateral block
#define NPT   16           // p-tiles per batch
#define SQ    16           // q-splits  -> chunk = 256 q
#define CHUNK 256
#define NBBIL (NBATCH * NPT * SQ)   // 512
#define NBCONV (NBATCH * NC)        // 42
// partial segments: per block 4 waves * 4 mtiles * 2 chtiles; 64 lanes * 4 halves each
#define SEGS_PER_S 1024    // NB*NPT*4*4*2
#define SEG_HALVES 256     // 64 lanes * 4

// ---- ws layout (float offsets) ----
#define OFF_QFEAT 0                  // [NB*P][8] fp32 {L*f0..L*f4, h, 0,0}
#define OFF_UT    65536              // [NB*P][24] fp32 log-unary
#define OFF_QSF   262144             // [NB][21][P] fp32 spatial out
#define OFF_G     434176             // [64][64] fp16 band-gaussian (2048 floats)
#define OFF_QH16  436224             // [NB][24][P] fp16 planar q (pads 21-23 zero)
#define OFF_QBFC  534528             // [1024 segs][256] fp32 reduced (frag order)
#define OFF_PART  796672             // [SQ][1024 segs][256] fp16 partials

// ---- LDS (bilat: 45568 B / conv: 27648 B) ----
#define LDS_BYTES 45568

__global__ __launch_bounds__(256) void setup_kernel(
    const float* __restrict__ unary, const float* __restrict__ ref,
    const float* __restrict__ kstd, float* __restrict__ ws,
    float* __restrict__ outq)
{
    int gid = blockIdx.x * 256 + threadIdx.x;
    // band-matrix G[y][y'] fp16 (separable factor of the 71x71 gaussian)
    if (gid < 4096) {
        float s = 0.f;
        for (int t = -KR; t <= KR; ++t) s += expf(-(float)(t * t) * (1.0f / 72.0f));
        int y = gid >> 6, yp = gid & 63;
        int d = y - yp;
        float v = (d >= -KR && d <= KR) ? expf(-(float)(d * d) * (1.0f / 72.0f)) / s : 0.f;
        ((half_t*)(ws + OFF_G))[gid] = (half_t)v;
    }
    if (gid >= NBATCH * NP) return;
    int n = gid >> 12, p = gid & (NP - 1);
    int y = p >> 6, x = p & 63;
    float k0 = kstd[0], k1 = kstd[1], k2 = kstd[2], k3 = kstd[3], k4 = kstd[4];
    const float* rp = ref + n * 3 * NP + p;
    float f0 = (float)y / k0;
    float f1 = (float)x / k1;
    float f2 = rp[0]      / k2;
    float f3 = rp[NP]     / k3;
    float f4 = rp[2 * NP] / k4;
    float sq = f0*f0 + f1*f1 + f2*f2 + f3*f3 + f4*f4;
    float h  = -0.5f * L2E * sq;       // exponent(p,q) = Sum f_p*(L*f_q) + h_p + h_q
    float* qf = ws + OFF_QFEAT + gid * 8;
    qf[0]=L2E*f0; qf[1]=L2E*f1; qf[2]=L2E*f2; qf[3]=L2E*f3; qf[4]=L2E*f4;
    qf[5]=h; qf[6]=0.f; qf[7]=0.f;

    float U[NC], e[NC];
    const float* up = unary + n * NC * NP + p;
    float m = -1e30f;
    for (int c = 0; c < NC; ++c) {
        float u = up[c * NP];
        u = fminf(fmaxf(u, 1e-5f), 1.0f);
        U[c] = logf(u);
        m = fmaxf(m, U[c]);
    }
    float ssum = 0.f;
    for (int c = 0; c < NC; ++c) { e[c] = EXP2F(L2E * (U[c] - m)); ssum += e[c]; }
    float inv = 1.0f / ssum;
    float* ut = ws + OFF_UT + gid * 24;
    half_t* qh = (half_t*)(ws + OFF_QH16);
    for (int c = 0; c < NC; ++c) {
        float qv = e[c] * inv;
        ut[c] = U[c];
        qh[(n * 24 + c) * NP + p] = (half_t)qv;
        outq[(n * NC + c) * NP + p] = qv;
    }
    ut[21] = 0.f; ut[22] = 0.f; ut[23] = 0.f;
    qh[(n * 24 + 21) * NP + p] = (half_t)0.f;
    qh[(n * 24 + 22) * NP + p] = (half_t)0.f;
    qh[(n * 24 + 23) * NP + p] = (half_t)0.f;
}

// L1: blocks [0,512): bilateral K-tile MFMA.  blocks [512,554): separable conv via MFMA.
__global__ __launch_bounds__(256) void bilat_conv_kernel(
    const float* __restrict__ qfeat,
    const half_t* __restrict__ qh16,
    const half_t* __restrict__ gmat,
    half_t* __restrict__ part,
    float* __restrict__ qsf)
{
    __shared__ __align__(16) char lds[LDS_BYTES];
    int b = blockIdx.x;
    int tid = threadIdx.x;
    int l = tid & 63, w = tid >> 6;

    if (b < NBBIL) {
        // ---- bilateral block: (n, pt, s) ----
        int n  = b & 1;
        int pt = (b >> 1) & (NPT - 1);
        int s  = b >> 5;
        float*  qfeatS = (float*)lds;                       // [256][8]   8 KB
        half_t* ktile  = (half_t*)(lds + 8192);             // [256][40] 20 KB
        half_t* qls    = (half_t*)(lds + 28672);            // [32][264] 16.9 KB

        // stage q-features (chunk of 256 records)
        {
            const float4* src = (const float4*)(qfeat + (size_t)(n * NP + s * CHUNK) * 8);
            float4* dst = (float4*)qfeatS;
            for (int i = tid; i < CHUNK * 2; i += 256) dst[i] = src[i];
        }
        // stage q-probs fp16: rows 0..20 from global, rows 21..31 zero
        {
            for (int i = tid; i < 21 * (CHUNK / 8); i += 256) {   // 672 b128 copies
                int c = i >> 5, g = i & 31;
                *(h8*)(qls + c * 264 + g * 8) =
                    *(const h8*)(qh16 + (size_t)(n * 24 + c) * NP + s * CHUNK + g * 8);
            }
            for (int i = tid; i < 11 * 33; i += 256) {            // zero pad rows
                int c = 21 + i / 33, g = i % 33;
                *(h8*)(qls + c * 264 + g * 8) = (h8)(half_t)0.f;
            }
        }
        // p-side features: 4 rows per lane, held all chunk (de-scale by 1/L2E)
        float pf[4][5], ph[4];
        #pragma unroll
        for (int r = 0; r < 4; ++r) {
            const float* fp = qfeat + (size_t)(n * NP + pt * PTILE + l + r * 64) * 8;
            #pragma unroll
            for (int i = 0; i < 5; ++i) pf[r][i] = fp[i] * RL2E;
            ph[r] = fp[5];
        }
        f4 acc[4][2];
        #pragma unroll
        for (int mt = 0; mt < 4; ++mt) {
            acc[mt][0] = (f4)0.f; acc[mt][1] = (f4)0.f;
        }
        __syncthreads();

        for (int step = 0; step < CHUNK / 32; ++step) {
            // Phase A: wave w computes K for q = step*32 + w*8 .. +8, all 256 p
            h8 kv[4];
            #pragma unroll
            for (int j = 0; j < 8; ++j) {
                int ql = step * 32 + w * 8 + j;
                float4 qa = *(const float4*)(qfeatS + ql * 8);
                float2 qb = *(const float2*)(qfeatS + ql * 8 + 4);
                #pragma unroll
                for (int r = 0; r < 4; ++r) {
                    float e = ph[r] + qb.y;
                    e = fmaf(pf[r][0], qa.x, e);
                    e = fmaf(pf[r][1], qa.y, e);
                    e = fmaf(pf[r][2], qa.z, e);
                    e = fmaf(pf[r][3], qa.w, e);
                    e = fmaf(pf[r][4], qb.x, e);
                    kv[r][j] = (half_t)EXP2F(e);
                }
            }
            #pragma unroll
            for (int r = 0; r < 4; ++r)
                *(h8*)(ktile + (size_t)(l + r * 64) * 40 + w * 8) = kv[r];
            __syncthreads();

            // Phase B: wave w contracts m-tiles w*4..w*4+3 against Q fp16
            h8 bf0 = *(const h8*)(qls + (size_t)(l & 15) * 264 + step * 32 + (l >> 4) * 8);
            h8 bf1 = *(const h8*)(qls + (size_t)(16 + (l & 15)) * 264 + step * 32 + (l >> 4) * 8);
            #pragma unroll
            for (int mt = 0; mt < 4; ++mt) {
                h8 af = *(const h8*)(ktile + (size_t)((w * 4 + mt) * 16 + (l & 15)) * 40 + (l >> 4) * 8);
                acc[mt][0] = MFMA16(af, bf0, acc[mt][0]);
                acc[mt][1] = MFMA16(af, bf1, acc[mt][1]);
            }
            __syncthreads();
        }
        // epilogue: raw C-fragment partials, fp16, coalesced b64
        #pragma unroll
        for (int mt = 0; mt < 4; ++mt) {
            #pragma unroll
            for (int cht = 0; cht < 2; ++cht) {
                int segFlat = ((((s * 2 + n) * NPT + pt) * 4 + w) * 4 + mt) * 2 + cht;
                h4 hv;
                hv[0] = (half_t)acc[mt][cht][0];
                hv[1] = (half_t)acc[mt][cht][1];
                hv[2] = (half_t)acc[mt][cht][2];
                hv[3] = (half_t)acc[mt][cht][3];
                *(h4*)(part + (size_t)segFlat * SEG_HALVES + l * 4) = hv;
            }
        }
    } else {
        // ---- conv block: one (n,c); qsf = G * Q * G  (G symmetric band) ----
        int cb = b - NBBIL;
        int n = cb / NC, c = cb % NC;
        half_t* qt = (half_t*)lds;                 // [64][72] Q^T
        half_t* gl = (half_t*)(lds + 9216);        // [64][72] G row-major
        half_t* dl = (half_t*)(lds + 18432);       // [64][72] intermediate

        for (int i = tid; i < 512; i += 256) {     // G: 4096 halves as b128
            int row = i >> 3, g = i & 7;
            *(h8*)(gl + row * 72 + g * 8) = *(const h8*)(gmat + row * 64 + g * 8);
        }
        const half_t* qsrc = qh16 + (size_t)(n * 24 + c) * NP;
        for (int i = tid; i < 512; i += 256) {     // stage Q transposed
            int row = i >> 3, g = i & 7;           // row=y, cols x=g*8..
            h8 v = *(const h8*)(qsrc + row * 64 + g * 8);
            #pragma unroll
            for (int k = 0; k < 8; ++k) qt[(g * 8 + k) * 72 + row] = v[k];
        }
        __syncthreads();

        int m0 = w * 16;
        f4 acc1[4];
        #pragma unroll
        for (int nt = 0; nt < 4; ++nt) acc1[nt] = (f4)0.f;
        #pragma unroll
        for (int ks = 0; ks < 2; ++ks) {
            h8 af = *(const h8*)(gl + (size_t)(m0 + (l & 15)) * 72 + ks * 32 + (l >> 4) * 8);
            #pragma unroll
            for (int nt = 0; nt < 4; ++nt) {
                h8 bf = *(const h8*)(qt + (size_t)(nt * 16 + (l & 15)) * 72 + ks * 32 + (l >> 4) * 8);
                acc1[nt] = MFMA16(af, bf, acc1[nt]);
            }
        }
        #pragma unroll
        for (int nt = 0; nt < 4; ++nt)
            #pragma unroll
            for (int r = 0; r < 4; ++r)
                dl[(size_t)(m0 + (l >> 4) * 4 + r) * 72 + nt * 16 + (l & 15)] = (half_t)acc1[nt][r];
        __syncthreads();

        f4 acc2[4];
        #pragma unroll
        for (int nt = 0; nt < 4; ++nt) acc2[nt] = (f4)0.f;
        #pragma unroll
        for (int ks = 0; ks < 2; ++ks) {
            h8 af = *(const h8*)(dl + (size_t)(m0 + (l & 15)) * 72 + ks * 32 + (l >> 4) * 8);
            #pragma unroll
            for (int nt = 0; nt < 4; ++nt) {
                h8 bf = *(const h8*)(gl + (size_t)(nt * 16 + (l & 15)) * 72 + ks * 32 + (l >> 4) * 8);
                acc2[nt] = MFMA16(af, bf, acc2[nt]);
            }
        }
        float* dst = qsf + (size_t)(n * NC + c) * NP;
        #pragma unroll
        for (int nt = 0; nt < 4; ++nt)
            #pragma unroll
            for (int r = 0; r < 4; ++r)
                dst[(size_t)(m0 + (l >> 4) * 4 + r) * 64 + nt * 16 + (l & 15)] = acc2[nt][r];
    }
}

// L2: reduce fp16 fragment partials over s -> fp32 qbfC (still fragment order)
__global__ __launch_bounds__(256) void reduce_kernel(
    const half_t* __restrict__ part, float* __restrict__ qbfC)
{
    int tIdx = blockIdx.x * 256 + threadIdx.x;      // [0, 65536)
    int segLocal = tIdx >> 6, lane = tIdx & 63;
    float a0 = 0.f, a1 = 0.f, a2 = 0.f, a3 = 0.f;
    for (int s = 0; s < SQ; ++s) {
        h4 v = *(const h4*)(part + ((size_t)(s * SEGS_PER_S + segLocal)) * SEG_HALVES + lane * 4);
        a0 += (float)v[0]; a1 += (float)v[1]; a2 += (float)v[2]; a3 += (float)v[3];
    }
    *(float4*)(qbfC + (size_t)segLocal * SEG_HALVES + lane * 4) = make_float4(a0, a1, a2, a3);
}

// L3: per-pixel logits + softmax; rewrite planar fp32 + fp16
__global__ __launch_bounds__(256) void update_kernel(
    const float* __restrict__ qbfC, const float* __restrict__ ut_,
    const float* __restrict__ qsf, float* __restrict__ outq,
    half_t* __restrict__ qh16)
{
    int gid = blockIdx.x * 256 + threadIdx.x;       // < NB*P = 8192
    int n = gid >> 12, p = gid & (NP - 1);
    int pt = p >> 8, pp = p & 255;
    int mt = pp >> 4, mrow = pp & 15;
    int wv = mt >> 2, mtl = mt & 3;
    int lg = mrow >> 2, reg = mrow & 3;
    int segBase = (((n * NPT + pt) * 4 + wv) * 4 + mtl) * 2;

    float qb[NC];
    #pragma unroll
    for (int c = 0; c < NC; ++c) {
        int cht = c >> 4, chL = c & 15;
        qb[c] = qbfC[(size_t)(segBase + cht) * SEG_HALVES + (lg * 16 + chL) * 4 + reg];
    }
    const float* ut = ut_ + (size_t)gid * 24;
    const float* qs = qsf + (size_t)n * NC * NP + p;
    float lg_[NC], e[NC];
    float m = -1e30f;
    #pragma unroll
    for (int c = 0; c < NC; ++c) {
        float li = ut[c] + 4.0f * qb[c] + 2.0f * qs[c * NP];
        lg_[c] = li;
        m = fmaxf(m, li);
    }
    float ssum = 0.f;
    #pragma unroll
    for (int c = 0; c < NC; ++c) { e[c] = EXP2F(L2E * (lg_[c] - m)); ssum += e[c]; }
    float inv = 1.0f / ssum;
    #pragma unroll
    for (int c = 0; c < NC; ++c) {
        float qv = e[c] * inv;
        outq[(size_t)(n * NC + c) * NP + p] = qv;
        qh16[(size_t)(n * 24 + c) * NP + p] = (half_t)qv;
    }
}

extern "C" void kernel_launch(void* const* d_in, const int* in_sizes, int n_in,
                              void* d_out, int out_size, void* d_ws, size_t ws_size,
                              hipStream_t stream)
{
    const float* unary = (const float*)d_in[0];
    const float* ref   = (const float*)d_in[1];
    const float* kstd  = (const float*)d_in[3];
    float* ws   = (float*)d_ws;
    float* outq = (float*)d_out;

    const float*  qfeat = ws + OFF_QFEAT;
    float*        ut    = ws + OFF_UT;
    float*        qsf   = ws + OFF_QSF;
    const half_t* gmat  = (const half_t*)(ws + OFF_G);
    half_t*       qh16  = (half_t*)(ws + OFF_QH16);
    float*        qbfC  = ws + OFF_QBFC;
    half_t*       part  = (half_t*)(ws + OFF_PART);

    setup_kernel<<<32, 256, 0, stream>>>(unary, ref, kstd, ws, outq);
    for (int it = 0; it < 5; ++it) {
        bilat_conv_kernel<<<NBBIL + NBCONV, 256, 0, stream>>>(qfeat, qh16, gmat, part, qsf);
        reduce_kernel<<<256, 256, 0, stream>>>(part, qbfC);
        update_kernel<<<32, 256, 0, stream>>>(qbfC, ut, qsf, outq, qh16);
    }
}

// Round 6
// 179.512 us; speedup vs baseline: 3.8812x; 1.0638x over previous
//
#include <hip/hip_runtime.h>
#include <math.h>

#ifndef __has_builtin
#define __has_builtin(x) 0
#endif
#if __has_builtin(__builtin_amdgcn_exp2f)
#define EXP2F(x) __builtin_amdgcn_exp2f(x)
#else
#define EXP2F(x) exp2f(x)
#endif

#define L2E  1.44269504088896340736f
#define RL2E 0.69314718055994530942f

#define NBATCH 2
#define NC 21
#define HH 64
#define WW 64
#define NP 4096
#define KR 35
#define KS 71

typedef _Float16 half_t;
typedef _Float16 h8 __attribute__((ext_vector_type(8)));
typedef _Float16 h4 __attribute__((ext_vector_type(4)));
typedef float f4 __attribute__((ext_vector_type(4)));
#define MFMA16(a, b, c) __builtin_amdgcn_mfma_f32_16x16x32_f16((a), (b), (c), 0, 0, 0)

// ---- tiling ----
#define PTILE 256          // p per bilateral block
#define NPT   16           // p-tiles per batch
#define SQ    16           // q-splits  -> chunk = 256 q
#define CHUNK 256
#define NBBIL (NBATCH * NPT * SQ)   // 512
#define NBCONV (NBATCH * NC)        // 42
// partial segments: per block 4 waves * 4 mtiles * 2 chtiles; 64 lanes * 4 halves each
#define SEGS_PER_S 1024    // NB*NPT*4*4*2
#define SEG_HALVES 256     // 64 lanes * 4

// ---- ws layout (float offsets) ----
#define OFF_QFEAT 0                  // [NB*P][8] fp32 {L*f0..L*f4, h, 0,0}
#define OFF_UT    65536              // [NB*P][24] fp32 log-unary
#define OFF_QSF   262144             // [NB][21][P] fp32 spatial out
#define OFF_G     434176             // [64][64] fp16 band-gaussian (2048 floats)
#define OFF_QH16  436224             // [NB][24][P] fp16 planar q (pads 21-23 zero)
#define OFF_QBFC  534528             // [1024 segs][256] fp32 reduced (frag order)
#define OFF_PART  796672             // [SQ][1024 segs][256] fp16 partials

// ---- LDS (bilat: 25088 B / conv: 27648 B) ----
#define LDS_BYTES 27648

__global__ __launch_bounds__(256) void setup_kernel(
    const float* __restrict__ unary, const float* __restrict__ ref,
    const float* __restrict__ kstd, float* __restrict__ ws,
    float* __restrict__ outq)
{
    int gid = blockIdx.x * 256 + threadIdx.x;
    // band-matrix G[y][y'] fp16 (separable factor of the 71x71 gaussian)
    if (gid < 4096) {
        float s = 0.f;
        for (int t = -KR; t <= KR; ++t) s += expf(-(float)(t * t) * (1.0f / 72.0f));
        int y = gid >> 6, yp = gid & 63;
        int d = y - yp;
        float v = (d >= -KR && d <= KR) ? expf(-(float)(d * d) * (1.0f / 72.0f)) / s : 0.f;
        ((half_t*)(ws + OFF_G))[gid] = (half_t)v;
    }
    if (gid >= NBATCH * NP) return;
    int n = gid >> 12, p = gid & (NP - 1);
    int y = p >> 6, x = p & 63;
    float k0 = kstd[0], k1 = kstd[1], k2 = kstd[2], k3 = kstd[3], k4 = kstd[4];
    const float* rp = ref + n * 3 * NP + p;
    float f0 = (float)y / k0;
    float f1 = (float)x / k1;
    float f2 = rp[0]      / k2;
    float f3 = rp[NP]     / k3;
    float f4 = rp[2 * NP] / k4;
    float sq = f0*f0 + f1*f1 + f2*f2 + f3*f3 + f4*f4;
    float h  = -0.5f * L2E * sq;       // exponent(p,q) = Sum f_p*(L*f_q) + h_p + h_q
    float* qf = ws + OFF_QFEAT + gid * 8;
    qf[0]=L2E*f0; qf[1]=L2E*f1; qf[2]=L2E*f2; qf[3]=L2E*f3; qf[4]=L2E*f4;
    qf[5]=h; qf[6]=0.f; qf[7]=0.f;

    float U[NC], e[NC];
    const float* up = unary + n * NC * NP + p;
    float m = -1e30f;
    for (int c = 0; c < NC; ++c) {
        float u = up[c * NP];
        u = fminf(fmaxf(u, 1e-5f), 1.0f);
        U[c] = logf(u);
        m = fmaxf(m, U[c]);
    }
    float ssum = 0.f;
    for (int c = 0; c < NC; ++c) { e[c] = EXP2F(L2E * (U[c] - m)); ssum += e[c]; }
    float inv = 1.0f / ssum;
    float* ut = ws + OFF_UT + gid * 24;
    half_t* qh = (half_t*)(ws + OFF_QH16);
    for (int c = 0; c < NC; ++c) {
        float qv = e[c] * inv;
        ut[c] = U[c];
        qh[(n * 24 + c) * NP + p] = (half_t)qv;
        outq[(n * NC + c) * NP + p] = qv;
    }
    ut[21] = 0.f; ut[22] = 0.f; ut[23] = 0.f;
    qh[(n * 24 + 21) * NP + p] = (half_t)0.f;
    qh[(n * 24 + 22) * NP + p] = (half_t)0.f;
    qh[(n * 24 + 23) * NP + p] = (half_t)0.f;
}

// L1: blocks [0,512): bilateral, K computed directly in A-fragment registers.
//     blocks [512,554): separable conv via MFMA.
__global__ __launch_bounds__(256) void bilat_conv_kernel(
    const float* __restrict__ qfeat,
    const half_t* __restrict__ qh16,
    const half_t* __restrict__ gmat,
    half_t* __restrict__ part,
    float* __restrict__ qsf)
{
    __shared__ __align__(16) char lds[LDS_BYTES];
    int b = blockIdx.x;
    int tid = threadIdx.x;
    int l = tid & 63, w = tid >> 6;

    if (b < NBBIL) {
        // ---- bilateral block: (n, pt, s) ----
        int n  = b & 1;
        int pt = (b >> 1) & (NPT - 1);
        int s  = b >> 5;
        float*  qfeatS = (float*)lds;                       // [256][8]   8 KB
        half_t* qls    = (half_t*)(lds + 8192);             // [32][264] 16.9 KB

        // stage q-features (chunk of 256 records)
        {
            const float4* src = (const float4*)(qfeat + (size_t)(n * NP + s * CHUNK) * 8);
            float4* dst = (float4*)qfeatS;
            for (int i = tid; i < CHUNK * 2; i += 256) dst[i] = src[i];
        }
        // stage q-probs fp16: rows 0..20 from global, rows 21..31 zero
        {
            for (int i = tid; i < 21 * (CHUNK / 8); i += 256) {   // 672 b128 copies
                int c = i >> 5, g = i & 31;
                *(h8*)(qls + c * 264 + g * 8) =
                    *(const h8*)(qh16 + (size_t)(n * 24 + c) * NP + s * CHUNK + g * 8);
            }
            for (int i = tid; i < 11 * 33; i += 256) {            // zero pad rows
                int c = 21 + i / 33, g = i % 33;
                *(h8*)(qls + c * 264 + g * 8) = (h8)(half_t)0.f;
            }
        }
        // p-side features: wave w owns m-tiles w*4..w*4+3; lane row = (l&15)
        // A-frag: lane l holds A[m=l&15][k=(l>>4)*8+j]  ->  compute K in-register
        float pf[4][5], ph[4];
        #pragma unroll
        for (int mt = 0; mt < 4; ++mt) {
            const float* fp = qfeat + (size_t)(n * NP + pt * PTILE + (w * 4 + mt) * 16 + (l & 15)) * 8;
            #pragma unroll
            for (int i = 0; i < 5; ++i) pf[mt][i] = fp[i] * RL2E;
            ph[mt] = fp[5];
        }
        f4 acc[4][2];
        #pragma unroll
        for (int mt = 0; mt < 4; ++mt) {
            acc[mt][0] = (f4)0.f; acc[mt][1] = (f4)0.f;
        }
        int kq = (l >> 4) * 8;   // this lane's k-offset within the 32-q step
        __syncthreads();

        for (int step = 0; step < CHUNK / 32; ++step) {
            // compute this lane's A-fragment K values for its 4 m-tiles
            h8 kv[4];
            #pragma unroll
            for (int j = 0; j < 8; ++j) {
                int ql = step * 32 + kq + j;
                float4 qa = *(const float4*)(qfeatS + ql * 8);
                float2 qb = *(const float2*)(qfeatS + ql * 8 + 4);
                #pragma unroll
                for (int mt = 0; mt < 4; ++mt) {
                    float e = ph[mt] + qb.y;
                    e = fmaf(pf[mt][0], qa.x, e);
                    e = fmaf(pf[mt][1], qa.y, e);
                    e = fmaf(pf[mt][2], qa.z, e);
                    e = fmaf(pf[mt][3], qa.w, e);
                    e = fmaf(pf[mt][4], qb.x, e);
                    kv[mt][j] = (half_t)EXP2F(e);
                }
            }
            h8 bf0 = *(const h8*)(qls + (size_t)(l & 15) * 264 + step * 32 + kq);
            h8 bf1 = *(const h8*)(qls + (size_t)(16 + (l & 15)) * 264 + step * 32 + kq);
            #pragma unroll
            for (int mt = 0; mt < 4; ++mt) {
                acc[mt][0] = MFMA16(kv[mt], bf0, acc[mt][0]);
                acc[mt][1] = MFMA16(kv[mt], bf1, acc[mt][1]);
            }
        }
        // epilogue: raw C-fragment partials, fp16, coalesced b64
        #pragma unroll
        for (int mt = 0; mt < 4; ++mt) {
            #pragma unroll
            for (int cht = 0; cht < 2; ++cht) {
                int segFlat = ((((s * 2 + n) * NPT + pt) * 4 + w) * 4 + mt) * 2 + cht;
                h4 hv;
                hv[0] = (half_t)acc[mt][cht][0];
                hv[1] = (half_t)acc[mt][cht][1];
                hv[2] = (half_t)acc[mt][cht][2];
                hv[3] = (half_t)acc[mt][cht][3];
                *(h4*)(part + (size_t)segFlat * SEG_HALVES + l * 4) = hv;
            }
        }
    } else {
        // ---- conv block: one (n,c); qsf = G * Q * G  (G symmetric band) ----
        int cb = b - NBBIL;
        int n = cb / NC, c = cb % NC;
        half_t* qt = (half_t*)lds;                 // [64][72] Q^T
        half_t* gl = (half_t*)(lds + 9216);        // [64][72] G row-major
        half_t* dl = (half_t*)(lds + 18432);       // [64][72] intermediate

        for (int i = tid; i < 512; i += 256) {     // G: 4096 halves as b128
            int row = i >> 3, g = i & 7;
            *(h8*)(gl + row * 72 + g * 8) = *(const h8*)(gmat + row * 64 + g * 8);
        }
        const half_t* qsrc = qh16 + (size_t)(n * 24 + c) * NP;
        for (int i = tid; i < 512; i += 256) {     // stage Q transposed
            int row = i >> 3, g = i & 7;           // row=y, cols x=g*8..
            h8 v = *(const h8*)(qsrc + row * 64 + g * 8);
            #pragma unroll
            for (int k = 0; k < 8; ++k) qt[(g * 8 + k) * 72 + row] = v[k];
        }
        __syncthreads();

        int m0 = w * 16;
        f4 acc1[4];
        #pragma unroll
        for (int nt = 0; nt < 4; ++nt) acc1[nt] = (f4)0.f;
        #pragma unroll
        for (int ks = 0; ks < 2; ++ks) {
            h8 af = *(const h8*)(gl + (size_t)(m0 + (l & 15)) * 72 + ks * 32 + (l >> 4) * 8);
            #pragma unroll
            for (int nt = 0; nt < 4; ++nt) {
                h8 bf = *(const h8*)(qt + (size_t)(nt * 16 + (l & 15)) * 72 + ks * 32 + (l >> 4) * 8);
                acc1[nt] = MFMA16(af, bf, acc1[nt]);
            }
        }
        #pragma unroll
        for (int nt = 0; nt < 4; ++nt)
            #pragma unroll
            for (int r = 0; r < 4; ++r)
                dl[(size_t)(m0 + (l >> 4) * 4 + r) * 72 + nt * 16 + (l & 15)] = (half_t)acc1[nt][r];
        __syncthreads();

        f4 acc2[4];
        #pragma unroll
        for (int nt = 0; nt < 4; ++nt) acc2[nt] = (f4)0.f;
        #pragma unroll
        for (int ks = 0; ks < 2; ++ks) {
            h8 af = *(const h8*)(dl + (size_t)(m0 + (l & 15)) * 72 + ks * 32 + (l >> 4) * 8);
            #pragma unroll
            for (int nt = 0; nt < 4; ++nt) {
                h8 bf = *(const h8*)(gl + (size_t)(nt * 16 + (l & 15)) * 72 + ks * 32 + (l >> 4) * 8);
                acc2[nt] = MFMA16(af, bf, acc2[nt]);
            }
        }
        float* dst = qsf + (size_t)(n * NC + c) * NP;
        #pragma unroll
        for (int nt = 0; nt < 4; ++nt)
            #pragma unroll
            for (int r = 0; r < 4; ++r)
                dst[(size_t)(m0 + (l >> 4) * 4 + r) * 64 + nt * 16 + (l & 15)] = acc2[nt][r];
    }
}

// L2: reduce fp16 fragment partials over s -> fp32 qbfC (still fragment order)
__global__ __launch_bounds__(256) void reduce_kernel(
    const half_t* __restrict__ part, float* __restrict__ qbfC)
{
    int tIdx = blockIdx.x * 256 + threadIdx.x;      // [0, 65536)
    int segLocal = tIdx >> 6, lane = tIdx & 63;
    float a0 = 0.f, a1 = 0.f, a2 = 0.f, a3 = 0.f;
    for (int s = 0; s < SQ; ++s) {
        h4 v = *(const h4*)(part + ((size_t)(s * SEGS_PER_S + segLocal)) * SEG_HALVES + lane * 4);
        a0 += (float)v[0]; a1 += (float)v[1]; a2 += (float)v[2]; a3 += (float)v[3];
    }
    *(float4*)(qbfC + (size_t)segLocal * SEG_HALVES + lane * 4) = make_float4(a0, a1, a2, a3);
}

// L3: per-pixel logits + softmax; rewrite planar fp32 + fp16
__global__ __launch_bounds__(256) void update_kernel(
    const float* __restrict__ qbfC, const float* __restrict__ ut_,
    const float* __restrict__ qsf, float* __restrict__ outq,
    half_t* __restrict__ qh16)
{
    int gid = blockIdx.x * 256 + threadIdx.x;       // < NB*P = 8192
    int n = gid >> 12, p = gid & (NP - 1);
    int pt = p >> 8, pp = p & 255;
    int mt = pp >> 4, mrow = pp & 15;
    int wv = mt >> 2, mtl = mt & 3;
    int lg = mrow >> 2, reg = mrow & 3;
    int segBase = (((n * NPT + pt) * 4 + wv) * 4 + mtl) * 2;

    float qb[NC];
    #pragma unroll
    for (int c = 0; c < NC; ++c) {
        int cht = c >> 4, chL = c & 15;
        qb[c] = qbfC[(size_t)(segBase + cht) * SEG_HALVES + (lg * 16 + chL) * 4 + reg];
    }
    const float* ut = ut_ + (size_t)gid * 24;
    const float* qs = qsf + (size_t)n * NC * NP + p;
    float lg_[NC], e[NC];
    float m = -1e30f;
    #pragma unroll
    for (int c = 0; c < NC; ++c) {
        float li = ut[c] + 4.0f * qb[c] + 2.0f * qs[c * NP];
        lg_[c] = li;
        m = fmaxf(m, li);
    }
    float ssum = 0.f;
    #pragma unroll
    for (int c = 0; c < NC; ++c) { e[c] = EXP2F(L2E * (lg_[c] - m)); ssum += e[c]; }
    float inv = 1.0f / ssum;
    #pragma unroll
    for (int c = 0; c < NC; ++c) {
        float qv = e[c] * inv;
        outq[(size_t)(n * NC + c) * NP + p] = qv;
        qh16[(size_t)(n * 24 + c) * NP + p] = (half_t)qv;
    }
}

extern "C" void kernel_launch(void* const* d_in, const int* in_sizes, int n_in,
                              void* d_out, int out_size, void* d_ws, size_t ws_size,
                              hipStream_t stream)
{
    const float* unary = (const float*)d_in[0];
    const float* ref   = (const float*)d_in[1];
    const float* kstd  = (const float*)d_in[3];
    float* ws   = (float*)d_ws;
    float* outq = (float*)d_out;

    const float*  qfeat = ws + OFF_QFEAT;
    float*        ut    = ws + OFF_UT;
    float*        qsf   = ws + OFF_QSF;
    const half_t* gmat  = (const half_t*)(ws + OFF_G);
    half_t*       qh16  = (half_t*)(ws + OFF_QH16);
    float*        qbfC  = ws + OFF_QBFC;
    half_t*       part  = (half_t*)(ws + OFF_PART);

    setup_kernel<<<32, 256, 0, stream>>>(unary, ref, kstd, ws, outq);
    for (int it = 0; it < 5; ++it) {
        bilat_conv_kernel<<<NBBIL + NBCONV, 256, 0, stream>>>(qfeat, qh16, gmat, part, qsf);
        reduce_kernel<<<256, 256, 0, stream>>>(part, qbfC);
        update_kernel<<<32, 256, 0, stream>>>(qbfC, ut, qsf, outq, qh16);
    }
}